// Round 4
// baseline (220.907 us; speedup 1.0000x reference)
//
#include <hip/hip_runtime.h>
#include <stdint.h>

#define NL      8192
#define NH      32768
#define FDIM    128
#define KSEL    32
#define QPW     8                 // queries per wave
#define NWAVES  4
#define BLOCK   (NWAVES * 64)
#define QPB     (NWAVES * QPW)    // 32 queries per block
#define BUFCAP  256
#define NGROUP  (NL / 64)         // 128 groups of 64 sorted points
#define NCELL   4096              // 16^3 Morton cells
#define TSCAN   4                 // nearest groups scanned for tau
#define MAXPASS 6

__device__ __forceinline__ int imin(int a, int b) { return a < b ? a : b; }
__device__ __forceinline__ int imax(int a, int b) { return a > b ? a : b; }

// ---- Morton cell id: 16^3 grid over [-4,4], cell size 0.5 ----
__device__ __forceinline__ uint32_t spread3(uint32_t x) {
    x &= 0xFu;
    x = (x | (x << 16)) & 0x030000FFu;
    x = (x | (x << 8))  & 0x0300F00Fu;
    x = (x | (x << 4))  & 0x030C30C3u;
    x = (x | (x << 2))  & 0x09249249u;
    return x;
}
__device__ __forceinline__ int cell_of(float px, float py, float pz) {
    int ix = (int)floorf((px + 4.0f) * 2.0f);
    int iy = (int)floorf((py + 4.0f) * 2.0f);
    int iz = (int)floorf((pz + 4.0f) * 2.0f);
    ix = imin(imax(ix, 0), 15); iy = imin(imax(iy, 0), 15); iz = imin(imax(iz, 0), 15);
    return (int)(spread3((uint32_t)ix) | (spread3((uint32_t)iy) << 1) | (spread3((uint32_t)iz) << 2));
}

// =================== K1: histogram of source cells ===================
__global__ void k_cell_count(const float* __restrict__ pos_l, int* __restrict__ hist) {
    const int i = blockIdx.x * 256 + threadIdx.x;
    if (i >= NL) return;
    const int c = cell_of(pos_l[i * 3 + 0], pos_l[i * 3 + 1], pos_l[i * 3 + 2]);
    atomicAdd(&hist[c], 1);
}

// =================== K2: exclusive scan (1 block) ===================
__global__ void k_cell_scan(const int* __restrict__ hist, int* __restrict__ cursor) {
    __shared__ int part[256];
    __shared__ int partpref[256];
    const int tid = threadIdx.x;
    int loc[16];
    int s = 0;
#pragma unroll
    for (int i = 0; i < 16; ++i) { loc[i] = s; s += hist[tid * 16 + i]; }
    part[tid] = s;
    __syncthreads();
    if (tid == 0) {
        int a = 0;
        for (int t = 0; t < 256; ++t) { partpref[t] = a; a += part[t]; }
    }
    __syncthreads();
    const int b = partpref[tid];
#pragma unroll
    for (int i = 0; i < 16; ++i) cursor[tid * 16 + i] = b + loc[i];
}

// =================== K3: scatter points into cell-sorted order ===================
__global__ void k_scatter(const float* __restrict__ pos_l, int* __restrict__ cursor,
                          float4* __restrict__ sorted, int* __restrict__ oidx) {
    const int i = blockIdx.x * 256 + threadIdx.x;
    if (i >= NL) return;
    const float px = pos_l[i * 3 + 0];
    const float py = pos_l[i * 3 + 1];
    const float pz = pos_l[i * 3 + 2];
    const int c = cell_of(px, py, pz);
    const int pos = atomicAdd(&cursor[c], 1);
    sorted[pos] = make_float4(px, py, pz, px * px + py * py + pz * pz);
    oidx[pos] = i;
}

// =================== K4: per-group bounding spheres ===================
__global__ void k_spheres(const float4* __restrict__ sorted, float4* __restrict__ spheres) {
    const int g = blockIdx.x;
    const int lane = threadIdx.x;
    const float4 p = sorted[g * 64 + lane];
    float sx = p.x, sy = p.y, sz = p.z;
#pragma unroll
    for (int j = 32; j >= 1; j >>= 1) {
        sx += __shfl_xor(sx, j); sy += __shfl_xor(sy, j); sz += __shfl_xor(sz, j);
    }
    const float cx = sx * (1.0f / 64.0f), cy = sy * (1.0f / 64.0f), cz = sz * (1.0f / 64.0f);
    const float dx = p.x - cx, dy = p.y - cy, dz = p.z - cz;
    float d2 = dx * dx + dy * dy + dz * dz;
#pragma unroll
    for (int j = 32; j >= 1; j >>= 1) d2 = fmaxf(d2, __shfl_xor(d2, j));
    if (lane == 0) spheres[g] = make_float4(cx, cy, cz, sqrtf(d2) + 1e-3f);
}

// =================== Main kernel ===================
__global__ __launch_bounds__(BLOCK, 4)
void knn_interp_kernel(const float* __restrict__ x,
                       const float* __restrict__ pos_h,
                       const float4* __restrict__ sorted,
                       const float4* __restrict__ spheres,
                       const int* __restrict__ oidx,
                       float* __restrict__ out)
{
    __shared__ float4   s_grp[NGROUP];                     // 2 KB
    __shared__ unsigned long long s_surv[NWAVES][QPW][2];  // 512 B
    __shared__ uint16_t s_idx[QPB][BUFCAP];                // 16 KB
    __shared__ float    s_w[QPB][KSEL];                    // 4 KB
    __shared__ int      s_wi[QPB][KSEL];                   // 4 KB

    const int tid   = threadIdx.x;
    const int lane  = tid & 63;
    const int wid   = tid >> 6;
    const int qbase = blockIdx.x * QPB + wid * QPW;
    const unsigned long long mlt = (1ull << lane) - 1ull;  // bits strictly below lane

    if (tid < NGROUP) s_grp[tid] = spheres[tid];
    __syncthreads();

    // lane owns group `lane` (h=0) and `lane+64` (h=1)
    const float4 cA = s_grp[lane];
    const float4 cB = s_grp[lane + 64];

    float qx[QPW], qy[QPW], qz[QPW], h2q[QPW], tauD[QPW];

    // ---- Phase 1: per query, pick 4 nearest groups (centroid argmin),
    //      scan their 256 points for tau, build sphere-survival masks ----
#pragma unroll
    for (int q = 0; q < QPW; ++q) {
        const int gq = qbase + q;
        qx[q] = pos_h[gq * 3 + 0];
        qy[q] = pos_h[gq * 3 + 1];
        qz[q] = pos_h[gq * 3 + 2];
        h2q[q] = fmaf(qx[q], qx[q], fmaf(qy[q], qy[q], qz[q] * qz[q]));

        const float dAx = qx[q] - cA.x, dAy = qy[q] - cA.y, dAz = qz[q] - cA.z;
        const float dA  = fmaf(dAx, dAx, fmaf(dAy, dAy, dAz * dAz));
        const float dBx = qx[q] - cB.x, dBy = qy[q] - cB.y, dBz = qz[q] - cB.z;
        const float dB  = fmaf(dBx, dBx, fmaf(dBy, dBy, dBz * dBz));

        // packed keys: (d2c top 24 bits | 8-bit group id) — d2c >= 0 so int order ok
        int kA = (int)((__float_as_uint(dA) & 0xFFFFFF00u) | (uint32_t)lane);
        int kB = (int)((__float_as_uint(dB) & 0xFFFFFF00u) | (uint32_t)(lane + 64));

        int gsel[TSCAN];
#pragma unroll
        for (int t = 0; t < TSCAN; ++t) {
            int m = imin(kA, kB);
#pragma unroll
            for (int j = 1; j <= 32; j <<= 1) m = imin(m, __shfl_xor(m, j));
            gsel[t] = m & 0xFF;            // unique ids -> exactly one reg matches
            if (kA == m) kA = 0x7FFFFFFF;
            if (kB == m) kB = 0x7FFFFFFF;
        }

        // D(p) = |p|^2 - 2 q.p  (monotone in d2 for fixed q; can be negative)
        float dmin = INFINITY;
#pragma unroll
        for (int t = 0; t < TSCAN; ++t) {
            const float4 p = sorted[(gsel[t] << 6) + lane];
            const float s = fmaf(qx[q], p.x, fmaf(qy[q], p.y, qz[q] * p.z));
            dmin = fminf(dmin, fmaf(-2.0f, s, p.w));
        }
        // bitonic-64 ascending sort of lane minima (R2-verified network);
        // element 31 >= 32nd smallest of the 256 scanned >= global 32nd.
        float v = dmin;
#pragma unroll
        for (int k = 2; k <= 64; k <<= 1) {
#pragma unroll
            for (int j = k >> 1; j >= 1; j >>= 1) {
                const float o     = __shfl_xor(v, j);
                const bool  up    = ((lane & k) == 0);
                const bool  lower = ((lane & j) == 0);
                v = (lower == up) ? fminf(v, o) : fmaxf(v, o);
            }
        }
        const float tau = __shfl(v, 31) + 1e-4f;
        tauD[q] = tau;

        const float st = sqrtf(fmaxf(tau + h2q[q], 0.0f)) + 1e-3f;  // distance-ball radius
        const float tA = st + cA.w, tB = st + cB.w;
        const unsigned long long bA = __ballot(dA <= tA * tA);
        const unsigned long long bB = __ballot(dB <= tB * tB);
        if (lane == 0) { s_surv[wid][q][0] = bA; s_surv[wid][q][1] = bB; }
    }

    // ---- Phase 2: per query: collect (with overflow tightening) -> exact
    //      fp64 re-rank -> top-32 -> gather + weighted average ----
#pragma unroll 1
    for (int q = 0; q < QPW; ++q) {
        const int QQ = wid * QPW + q;
        const int gq = qbase + q;
        float tau = tauD[q];
        int M = 0;

#pragma unroll 1
        for (int pass = 0; pass < MAXPASS; ++pass) {
            M = 0;
#pragma unroll 1
            for (int h = 0; h < 2; ++h) {
                unsigned long long mm = s_surv[wid][q][h];
                while (mm) {
                    const int g = (h << 6) + __builtin_ctzll(mm);
                    mm &= mm - 1;
                    const float4 p = sorted[(g << 6) + lane];
                    const float s = fmaf(qx[q], p.x, fmaf(qy[q], p.y, qz[q] * p.z));
                    const float D = fmaf(-2.0f, s, p.w);
                    const bool hit = (D <= tau);
                    const unsigned long long b = __ballot(hit);
                    if (b) {
                        const int o = M + (int)__popcll(b & mlt);
                        if (hit && o < BUFCAP) s_idx[QQ][o] = (uint16_t)((g << 6) + lane);
                        M += (int)__popcll(b);
                    }
                }
            }
            if (M <= BUFCAP) break;
            // overflow: tighten tau to the exact 32nd-smallest d2 of the 256
            // buffered candidates (order stat of a subset => still >= global
            // 32nd). Each pass excludes >= ~220 buffered entries => terminates.
            int kk[4];
#pragma unroll
            for (int r = 0; r < 4; ++r) {
                const int idx = (int)s_idx[QQ][64 * r + lane];
                const float4 c = sorted[idx];
                const float s = fmaf(qx[q], c.x, fmaf(qy[q], c.y, qz[q] * c.z));
                const float d2 = fmaxf(fmaf(-2.0f, s, c.w) + h2q[q], 0.0f);
                kk[r] = __float_as_int(d2);   // >= 0 -> int order == float order
            }
            int lo = 0, hi = 0x7F800000;
            while (lo < hi) {
                const int mid = (int)(((unsigned)lo + (unsigned)hi) >> 1);
                int cnt = 0;
#pragma unroll
                for (int r = 0; r < 4; ++r)
                    cnt += (int)__popcll(__ballot(kk[r] <= mid));
                if (cnt >= KSEL) hi = mid; else lo = mid + 1;
            }
            tau = __int_as_float(lo) - h2q[q] + 1e-4f;   // back to D-space + margin
        }
        if (M > BUFCAP) M = BUFCAP;

        // -------- exact fp64 re-rank + top-32 selection --------
        const double ax = (double)qx[q], ay = (double)qy[q], az = (double)qz[q];
        if (M <= 128) {
            // R2-verified bitonic-128, 2 elems/lane
            const int i0 = (2 * lane     < M) ? (int)s_idx[QQ][2 * lane]     : -1;
            const int i1 = (2 * lane + 1 < M) ? (int)s_idx[QQ][2 * lane + 1] : -1;
            float f0 = INFINITY, f1 = INFINITY;
            if (i0 >= 0) {
                const float4 c = sorted[i0];
                const double dx = (double)c.x - ax, dy = (double)c.y - ay, dz = (double)c.z - az;
                f0 = (float)(dx * dx + dy * dy + dz * dz);
            }
            if (i1 >= 0) {
                const float4 c = sorted[i1];
                const double dx = (double)c.x - ax, dy = (double)c.y - ay, dz = (double)c.z - az;
                f1 = (float)(dx * dx + dy * dy + dz * dz);
            }
            int v0 = __float_as_int(f0);
            int v1 = __float_as_int(f1);
#pragma unroll
            for (int k = 2; k <= 128; k <<= 1) {
                const bool up = ((lane & (k >> 1)) == 0);
#pragma unroll
                for (int j = k >> 1; j >= 2; j >>= 1) {
                    const int  xo    = j >> 1;
                    const bool lower = ((lane & xo) == 0);
                    const int o0 = __shfl_xor(v0, xo);
                    const int o1 = __shfl_xor(v1, xo);
                    v0 = (lower == up) ? imin(v0, o0) : imax(v0, o0);
                    v1 = (lower == up) ? imin(v1, o1) : imax(v1, o1);
                }
                const int mn = imin(v0, v1), mx = imax(v0, v1);  // j == 1
                v0 = up ? mn : mx;
                v1 = up ? mx : mn;
            }
            const int tau32 = __shfl(v1, 15);   // element 31 = 32nd smallest
            const bool a0 = (i0 >= 0) && (__float_as_int(f0) <= tau32);
            const bool a1 = (i1 >= 0) && (__float_as_int(f1) <= tau32);
            const unsigned long long b0 = __ballot(a0);
            const unsigned long long b1 = __ballot(a1);
            const int base = (int)__popcll(b0 & mlt) + (int)__popcll(b1 & mlt);
            const int p0 = base;
            const int p1 = base + (a0 ? 1 : 0);
            if (a0 && p0 < KSEL) { s_w[QQ][p0] = 1.0f / fmaxf(f0, 1e-16f); s_wi[QQ][p0] = oidx[i0]; }
            if (a1 && p1 < KSEL) { s_w[QQ][p1] = 1.0f / fmaxf(f1, 1e-16f); s_wi[QQ][p1] = oidx[i1]; }
        } else {
            // rare path (128 < M <= 256): binary-search rank select, 4/lane
            int ii[4]; float ff[4]; int kk_[4];
#pragma unroll
            for (int r = 0; r < 4; ++r) {
                const int e = 4 * lane + r;
                ii[r] = (e < M) ? (int)s_idx[QQ][e] : -1;
                ff[r] = INFINITY;
                if (ii[r] >= 0) {
                    const float4 c = sorted[ii[r]];
                    const double dx = (double)c.x - ax, dy = (double)c.y - ay, dz = (double)c.z - az;
                    ff[r] = (float)(dx * dx + dy * dy + dz * dz);
                }
                kk_[r] = __float_as_int(ff[r]);
            }
            int lo = 0, hi = 0x7F800000;
            while (lo < hi) {
                const int mid = (int)(((unsigned)lo + (unsigned)hi) >> 1);
                int cnt = 0;
#pragma unroll
                for (int r = 0; r < 4; ++r)
                    cnt += (int)__popcll(__ballot(ii[r] >= 0 && kk_[r] <= mid));
                if (cnt >= KSEL) hi = mid; else lo = mid + 1;
            }
            const int tau32 = lo;
            bool a[4]; unsigned long long b[4];
#pragma unroll
            for (int r = 0; r < 4; ++r) {
                a[r] = (ii[r] >= 0) && (kk_[r] <= tau32);
                b[r] = __ballot(a[r]);
            }
            int base = 0;
#pragma unroll
            for (int r = 0; r < 4; ++r) base += (int)__popcll(b[r] & mlt);
            int pref = 0;
#pragma unroll
            for (int r = 0; r < 4; ++r) {
                const int p = base + pref;
                if (a[r] && p < KSEL) { s_w[QQ][p] = 1.0f / fmaxf(ff[r], 1e-16f); s_wi[QQ][p] = oidx[ii[r]]; }
                pref += (a[r] ? 1 : 0);
            }
        }

        // -------- gather + inverse-d2 weighted average --------
        float acc0 = 0.0f, acc1 = 0.0f, wsum = 0.0f;
#pragma unroll 8
        for (int t = 0; t < KSEL; ++t) {
            const float w   = s_w[QQ][t];
            const int   idx = s_wi[QQ][t];
            const float* row = x + (size_t)idx * FDIM;
            acc0 = fmaf(w, row[lane], acc0);
            acc1 = fmaf(w, row[lane + 64], acc1);
            wsum += w;
        }
        const float invw = 1.0f / wsum;
        out[(size_t)gq * FDIM + lane]      = acc0 * invw;
        out[(size_t)gq * FDIM + 64 + lane] = acc1 * invw;
    }
}

extern "C" void kernel_launch(void* const* d_in, const int* in_sizes, int n_in,
                              void* d_out, int out_size, void* d_ws, size_t ws_size,
                              hipStream_t stream) {
    const float* x     = (const float*)d_in[0];
    const float* pos_l = (const float*)d_in[1];
    const float* pos_h = (const float*)d_in[2];
    float* out = (float*)d_out;

    char* ws = (char*)d_ws;
    int*    hist    = (int*)(ws + 0);              // 16 KB
    int*    cursor  = (int*)(ws + 16384);          // 16 KB
    float4* spheres = (float4*)(ws + 32768);       // 2 KB
    float4* sorted  = (float4*)(ws + 65536);       // 128 KB
    int*    oidx    = (int*)(ws + 65536 + 131072); // 32 KB

    hipMemsetAsync(hist, 0, NCELL * sizeof(int), stream);
    hipLaunchKernelGGL(k_cell_count, dim3(NL / 256), dim3(256), 0, stream, pos_l, hist);
    hipLaunchKernelGGL(k_cell_scan, dim3(1), dim3(256), 0, stream, hist, cursor);
    hipLaunchKernelGGL(k_scatter, dim3(NL / 256), dim3(256), 0, stream, pos_l, cursor, sorted, oidx);
    hipLaunchKernelGGL(k_spheres, dim3(NGROUP), dim3(64), 0, stream, sorted, spheres);
    hipLaunchKernelGGL(knn_interp_kernel, dim3(NH / QPB), dim3(BLOCK), 0, stream,
                       x, pos_h, sorted, spheres, oidx, out);
}